// Round 5
// baseline (114.470 us; speedup 1.0000x reference)
//
#include <hip/hip_runtime.h>
#include <math.h>

#define T_ 1024

__device__ __forceinline__ unsigned icode(int v) {
    return (v < 0) ? (0x80000000u | (unsigned)(-v)) : (unsigned)v;
}

// cos_sim on sign|abs codes; bit-exact vs reference (absmax 0 in R1/R3/R4)
__device__ __forceinline__ float cosc(unsigned ca, unsigned cb) {
    unsigned y = ca ^ cb;                       // low31: |a|^|b|, top: sign product
    int x = (int)(y & 0x7fffffffu) + 1;
    float m = fmaf((float)__clz(x), 0.0625f, -1.0f);   // 1 - e/16 (exact)
    return __uint_as_float(__float_as_uint(m) ^ (y & 0x80000000u));
}

__device__ __forceinline__ int cnc_val(int c, int sl, const int* rn, int p) {
    if (c == 32) return sl;
    int cc = (c < 32) ? c : (c - 33);
    int h = cc >> 1, k = cc & 1;
    int m = rn[h * 16 + k * 8 + p] & ((1 << h) - 1);
    int v = (sl ^ (1 << h)) ^ m;
    return (c < 32) ? v : -v;
}

__global__ __launch_bounds__(512, 4) void critigraph_kernel(
    const int* __restrict__ sta_loc,      // (T, 8)
    const int* __restrict__ nei_loc,      // (T, 64, 8)
    const int* __restrict__ rand_numbers, // (T, 16, 2, 8)
    const float* __restrict__ sta_emb,    // (T, 256)
    const float* __restrict__ nei_emb,    // (T, 64, 256)
    const float* __restrict__ mask,       // (T, 64)
    const float* __restrict__ rand_vals,  // (T, 8)
    const float* __restrict__ t_rand,     // (T,)
    float* __restrict__ out_sel,          // (T, 8)
    float* __restrict__ out_loss)         // (T,)
{
    const int t = blockIdx.x;
    const int tid = threadIdx.x;           // 0..511
    const int srow = tid >> 3, j8 = tid & 7;   // 8 lanes per s-row (eu & int side)
    const int c = tid >> 3, p = tid & 7;       // loss: one column (c,p) per thread

    __shared__ __align__(16) float    s_sta[256];
    __shared__ __align__(16) unsigned s_nlc[512];   // sign|abs codes of nei_loc
    __shared__ __align__(16) int      s_rn[256];
    __shared__ __align__(8)  float2   s_cg[512];    // (code, css-cs) per (s,p)
    __shared__ __align__(8)  float2   s_ew[64];     // (eu, w) per s
    __shared__ float  s_loss[520];
    __shared__ int    s_sl[8];
    __shared__ unsigned s_slc[8];
    __shared__ float  s_m[64];
    __shared__ float  s_rv[8];
    __shared__ float  s_lth;

    // ---- staging loads FIRST (vmcnt retires in issue order) ----
    float stav = (tid < 256) ? sta_emb[t * 256 + tid] : 0.f;
    int   nlv  = nei_loc[t * 512 + tid];
    int   rnv  = (tid < 256) ? rand_numbers[t * 256 + tid] : 0;
    int slv = 0; float rvv = 0.f;
    if (tid < 8) { slv = sta_loc[t * 8 + tid]; rvv = rand_vals[t * 8 + tid]; }
    float mv = (tid < 64) ? mask[t * 64 + tid] : 0.f;
    float trv = t_rand[t];

    // ---- nei_emb loads AFTER: drain inside the dot loop ----
    const float4* nrow = reinterpret_cast<const float4*>(nei_emb + (size_t)t * 64 * 256);
    float4 nv[8];
#pragma unroll
    for (int i = 0; i < 8; i++) nv[i] = nrow[srow * 64 + i * 8 + j8];

    if (tid < 256) { s_sta[tid] = stav; s_rn[tid] = rnv; }
    s_nlc[tid] = icode(nlv);
    if (tid < 8) { s_sl[tid] = slv; s_slc[tid] = icode(slv); s_rv[tid] = rvv; }
    if (tid < 64) s_m[tid] = mv;
    __syncthreads();   // sync1

    // ================= phase A (no internal barriers) =================
    // lth on wave 1 (mask is 0/1: sum exact in any order)
    if ((tid >> 6) == 1) {
        float x = s_m[tid & 63];
#pragma unroll
        for (int off = 32; off; off >>= 1) x += __shfl_xor(x, off, 64);
        if ((tid & 63) == 0) s_lth = x + 1e-12f;
    }

    // int side: thread handles (s=srow, p=j8); css redundant per 8 threads
    // (8 cosc each; exact multiples of 1/16 -> order-independent)
    {
        const uint4* nl4 = reinterpret_cast<const uint4*>(s_nlc);
        uint4 ra = nl4[srow * 2], rb = nl4[srow * 2 + 1];
        unsigned nn[8] = {ra.x, ra.y, ra.z, ra.w, rb.x, rb.y, rb.z, rb.w};
        float css = 0.f, csm[8];
#pragma unroll
        for (int i = 0; i < 8; i++) { csm[i] = cosc(s_slc[i], nn[i]); css += csm[i]; }
        s_cg[srow * 8 + j8] = make_float2(__uint_as_float(nn[j8]), css - csm[j8]);
    }

    // eu side: dot + nei-norm + sta-norm, 8 lanes per row (32 elems each)
    {
        const float4* st4 = reinterpret_cast<const float4*>(s_sta);
        float d0 = 0.f, n0 = 0.f, a0 = 0.f;
#pragma unroll
        for (int i = 0; i < 8; i++) {
            float4 sv = st4[i * 8 + j8];
            float4 nn = nv[i];
            d0 = fmaf(nn.x, sv.x, d0); d0 = fmaf(nn.y, sv.y, d0);
            d0 = fmaf(nn.z, sv.z, d0); d0 = fmaf(nn.w, sv.w, d0);
            n0 = fmaf(nn.x, nn.x, n0); n0 = fmaf(nn.y, nn.y, n0);
            n0 = fmaf(nn.z, nn.z, n0); n0 = fmaf(nn.w, nn.w, n0);
            a0 = fmaf(sv.x, sv.x, a0); a0 = fmaf(sv.y, sv.y, a0);
            a0 = fmaf(sv.z, sv.z, a0); a0 = fmaf(sv.w, sv.w, a0);
        }
        d0 += __shfl_xor(d0, 1, 64); d0 += __shfl_xor(d0, 2, 64); d0 += __shfl_xor(d0, 4, 64);
        n0 += __shfl_xor(n0, 1, 64); n0 += __shfl_xor(n0, 2, 64); n0 += __shfl_xor(n0, 4, 64);
        a0 += __shfl_xor(a0, 1, 64); a0 += __shfl_xor(a0, 2, 64); a0 += __shfl_xor(a0, 4, 64);
        if (j8 == 0) {
            float eun = d0 * (1.0f / sqrtf(n0));
            float eu  = eun * (1.0f / sqrtf(a0));
            float w   = fabsf(eu) * s_m[srow];
            s_ew[srow] = make_float2(eu, w);
        }
    }

    // candidate precompute (needs only staged ints)
    unsigned avc = icode(cnc_val(c, s_sl[p], s_rn, p));
    unsigned avc64 = 0;
    if (tid < 8) avc64 = icode(cnc_val(64, s_sl[tid], s_rn, tid));
    __syncthreads();   // sync2

    // ================= loss: one column per thread =================
    {
        float acc = 0.f;
#pragma unroll 4
        for (int s = 0; s < 64; s++) {
            float2 cg = s_cg[s * 8 + p];
            float2 ew = s_ew[s];                     // wave-uniform broadcast
            unsigned y = avc ^ __float_as_uint(cg.x);
            int x = (int)(y & 0x7fffffffu) + 1;
            float m1 = fmaf((float)__clz(x), 0.0625f, -1.0f);
            float cc = __uint_as_float(__float_as_uint(m1) ^ (y & 0x80000000u));
            float d = fmaf(cg.y + cc, 0.125f, -ew.x);  // exact numerator, 1 rounding
            acc = fmaf(d * d, ew.y, acc);
        }
        float lth = s_lth;
        s_loss[c * 8 + p] = acc / lth;
        if (tid < 8) {   // extra column c = 64
            float a64 = 0.f;
            for (int s = 0; s < 64; s++) {
                float2 cg = s_cg[s * 8 + tid];
                float2 ew = s_ew[s];
                unsigned y = avc64 ^ __float_as_uint(cg.x);
                int x = (int)(y & 0x7fffffffu) + 1;
                float m1 = fmaf((float)__clz(x), 0.0625f, -1.0f);
                float cc = __uint_as_float(__float_as_uint(m1) ^ (y & 0x80000000u));
                float d = fmaf(cg.y + cc, 0.125f, -ew.x);
                a64 = fmaf(d * d, ew.y, a64);
            }
            s_loss[512 + tid] = a64 / lth;
        }
    }
    __syncthreads();   // sync3

    // ================= wave-0 epilogue (argmin + rank-select + outputs) =====
    if (tid < 64) {
        const int pp = tid >> 3, g = tid & 7;
        float bv = s_loss[g * 8 + pp];
        int bi = g;
#pragma unroll
        for (int k = 1; k < 8; k++) {            // ascending c: first-min tie-break
            float vv = s_loss[(g + 8 * k) * 8 + pp];
            if (vv < bv) { bv = vv; bi = g + 8 * k; }
        }
        if (g == 0) {
            float vv = s_loss[512 + pp];         // c = 64
            if (vv < bv) { bv = vv; bi = 64; }
        }
#pragma unroll
        for (int off = 1; off < 8; off <<= 1) {  // lexicographic butterfly
            float ov = __shfl_xor(bv, off, 64);
            int   oi = __shfl_xor(bi, off, 64);
            if (ov < bv || (ov == bv && oi < bi)) { bv = ov; bi = oi; }
        }
        // stable-argsort rank of pp among rand_vals; top-4 <=> rank < 4
        bool sel = trv < 0.8f;
        float rme = s_rv[pp];
        int rank = 0;
#pragma unroll
        for (int p2 = 0; p2 < 8; p2++) {
            float ro = s_rv[p2];
            rank += (ro < rme || (ro == rme && p2 < pp)) ? 1 : 0;
        }
        int cidx = (rank < 4 && sel) ? bi : 32;
        if (g == 0)
            out_sel[t * 8 + pp] = (float)cnc_val(cidx, s_sl[pp], s_rn, pp);
        // real_loss: gather cidx via shuffle, serial ascending sum on lane 0
        float a = 0.f;
#pragma unroll
        for (int p2 = 0; p2 < 8; p2++) {
            int cx = __shfl(cidx, p2 * 8, 64);
            a += s_loss[cx * 8 + p2];
        }
        if (tid == 0) out_loss[t] = a * 0.125f;
    }
}

extern "C" void kernel_launch(void* const* d_in, const int* in_sizes, int n_in,
                              void* d_out, int out_size, void* d_ws, size_t ws_size,
                              hipStream_t stream) {
    const int*   sta_loc      = (const int*)d_in[0];
    const int*   nei_loc      = (const int*)d_in[1];
    const int*   rand_numbers = (const int*)d_in[2];
    const float* sta_emb      = (const float*)d_in[3];
    const float* nei_emb      = (const float*)d_in[4];
    const float* mask         = (const float*)d_in[5];
    const float* rand_vals    = (const float*)d_in[6];
    const float* t_rand       = (const float*)d_in[7];

    float* out_sel  = (float*)d_out;
    float* out_loss = out_sel + T_ * 8;

    critigraph_kernel<<<T_, 512, 0, stream>>>(
        sta_loc, nei_loc, rand_numbers, sta_emb, nei_emb, mask,
        rand_vals, t_rand, out_sel, out_loss);
}